// Round 1
// baseline (1331.886 us; speedup 1.0000x reference)
//
#include <hip/hip_runtime.h>
#include <hip/hip_bf16.h>
#include <stdint.h>
#include <stddef.h>

#define B_  8
#define S_  4096
#define H_  1024
#define NH_ 16
#define HD_ 64

typedef __bf16 bf16x8 __attribute__((ext_vector_type(8)));
typedef float  floatx4 __attribute__((ext_vector_type(4)));

__device__ __forceinline__ float bf2f(unsigned short u) {
    union { unsigned int i; float f; } x;
    x.i = ((unsigned int)u) << 16;
    return x.f;
}
__device__ __forceinline__ unsigned short f2bf(float f) {
    union { float f; unsigned int i; } x;
    x.f = f;
    return (unsigned short)((x.i + 0x7FFFu + ((x.i >> 16) & 1u)) >> 16);
}

// ---------------- conversion: fp32 -> bf16, vectorized x4 ----------------
__global__ __launch_bounds__(256) void k_f32_to_bf16(const float* __restrict__ src,
                                                     unsigned short* __restrict__ dst,
                                                     int n4) {
    int idx = blockIdx.x * 256 + threadIdx.x;
    if (idx >= n4) return;
    float4 v = ((const float4*)src)[idx];
    ushort4 o;
    o.x = f2bf(v.x); o.y = f2bf(v.y); o.z = f2bf(v.z); o.w = f2bf(v.w);
    ((ushort4*)dst)[idx] = o;
}

// ---------------- transpose-convert: W[k][n] fp32 -> WT[n][k] bf16 ----------------
__global__ __launch_bounds__(256) void k_transpose_bf16(const float* __restrict__ w,
                                                        unsigned short* __restrict__ wt) {
    int idx = blockIdx.x * 256 + threadIdx.x;   // 0 .. H*H-1
    int k = idx >> 10, n = idx & (H_ - 1);
    wt[(n << 10) | k] = f2bf(w[idx]);
}

// ---------------- main MFMA GEMM: C[M][N] = A[M][K] @ B[K][N] (+bias) ----------------
// A bf16 row-major [M][K]; BT bf16 [N][K] (i.e. B transposed).
// MODE 0: C written as bf16.  MODE 1: C written as fp32 with += bf2f(addsrc) (final output).
template <int MODE>
__global__ __launch_bounds__(256) void k_gemm_bt(const unsigned short* __restrict__ A,
                                                 const unsigned short* __restrict__ BT,
                                                 const float* __restrict__ bias,
                                                 void* __restrict__ Cout,
                                                 const unsigned short* __restrict__ addsrc,
                                                 int M, int N, int K) {
    constexpr int BM = 128, BN = 128, BK = 32, LDSW = 40; // pad 32->40 elems: 80B rows, conflict-free b128
    __shared__ unsigned short As[BM * LDSW];
    __shared__ unsigned short Bs[BN * LDSW];

    const int tid  = threadIdx.x;
    const int wave = tid >> 6, lane = tid & 63;
    const int quad = lane >> 4, m16 = lane & 15;
    const int wm = wave >> 1, wn = wave & 1;
    const int rowBase = blockIdx.y * BM;
    const int colBase = blockIdx.x * BN;

    floatx4 acc[4][4] = {};

    // staging: thread t loads row ar, 16-elem chunk ac (32 B = 2x uint4)
    const int ar = tid >> 1;
    const int ac = tid & 1;
    const uint4* agp = (const uint4*)(A + (size_t)(rowBase + ar) * K + ac * 16);
    const uint4* bgp = (const uint4*)(BT + (size_t)(colBase + ar) * K + ac * 16);
    uint4* asp = (uint4*)(As + ar * LDSW + ac * 16);
    uint4* bsp = (uint4*)(Bs + ar * LDSW + ac * 16);

    for (int kt = 0; kt < K; kt += BK) {
        uint4 a0 = agp[0], a1 = agp[1];
        uint4 b0 = bgp[0], b1 = bgp[1];
        agp += BK / 8; bgp += BK / 8;
        __syncthreads();
        asp[0] = a0; asp[1] = a1;
        bsp[0] = b0; bsp[1] = b1;
        __syncthreads();
        bf16x8 af[4], bfr[4];
#pragma unroll
        for (int i = 0; i < 4; i++)
            af[i] = *(const bf16x8*)(As + (wm * 64 + i * 16 + m16) * LDSW + quad * 8);
#pragma unroll
        for (int j = 0; j < 4; j++)
            bfr[j] = *(const bf16x8*)(Bs + (wn * 64 + j * 16 + m16) * LDSW + quad * 8);
#pragma unroll
        for (int i = 0; i < 4; i++)
#pragma unroll
            for (int j = 0; j < 4; j++)
                acc[i][j] = __builtin_amdgcn_mfma_f32_16x16x32_bf16(af[i], bfr[j], acc[i][j], 0, 0, 0);
    }

    // epilogue: D row = (lane>>4)*4 + r, col = lane&15  [measured layout, m89/m91]
#pragma unroll
    for (int i = 0; i < 4; i++) {
        const int row0 = rowBase + wm * 64 + i * 16 + quad * 4;
#pragma unroll
        for (int j = 0; j < 4; j++) {
            const int col = colBase + wn * 64 + j * 16 + m16;
            const float bv = bias[col];
#pragma unroll
            for (int r = 0; r < 4; r++) {
                const size_t off = (size_t)(row0 + r) * N + col;
                const float v = acc[i][j][r] + bv;
                if constexpr (MODE == 0) {
                    ((unsigned short*)Cout)[off] = f2bf(v);
                } else {
                    ((float*)Cout)[off] = v + bf2f(addsrc[off]);
                }
            }
        }
    }
}

// ---------------- score: qs[b][n][s] = (A[b,s,:]·W[:,n] + bias[n])*scale + mask[b][s] ----------------
__global__ __launch_bounds__(256) void k_score(const unsigned short* __restrict__ A, // [B*S][H] bf16
                                               const float* __restrict__ W,          // [H][NH] fp32
                                               const float* __restrict__ bias,       // [NH]
                                               const float* __restrict__ mask,       // [B][S]
                                               float* __restrict__ out) {            // [B][NH][S]
    __shared__ float Ws[H_ * NH_]; // 64 KB
    const int tid = threadIdx.x;
    for (int i = tid; i < H_ * NH_; i += 256) Ws[i] = W[i];
    __syncthreads();
    const int row = blockIdx.x * 16 + (tid >> 4); // global (b,s) row
    const int n = tid & 15;
    const int b = row >> 12, s = row & (S_ - 1);
    const unsigned short* arow = A + (size_t)row * H_;
    float dot = 0.f;
    for (int h = 0; h < H_; h += 8) {
        union { uint4 v; unsigned short u[8]; } x;
        x.v = *(const uint4*)(arow + h);
#pragma unroll
        for (int e = 0; e < 8; e++)
            dot += bf2f(x.u[e]) * Ws[(h + e) * NH_ + n];
    }
    out[((size_t)(b * NH_ + n)) * S_ + s] = (dot + bias[n]) * 0.125f + mask[row];
}

// ---------------- softmax over S, one block per (b,n) row ----------------
__global__ __launch_bounds__(256) void k_softmax(float* __restrict__ p) {
    float* row = p + (size_t)blockIdx.x * S_;
    const int tid = threadIdx.x;
    const int lane = tid & 63, wave = tid >> 6;
    __shared__ float red[4];

    float mx = -1e30f;
    for (int i = tid; i < S_; i += 256) mx = fmaxf(mx, row[i]);
#pragma unroll
    for (int off = 32; off > 0; off >>= 1) mx = fmaxf(mx, __shfl_xor(mx, off, 64));
    if (lane == 0) red[wave] = mx;
    __syncthreads();
    mx = fmaxf(fmaxf(red[0], red[1]), fmaxf(red[2], red[3]));
    __syncthreads();

    float sum = 0.f;
    for (int i = tid; i < S_; i += 256) {
        float e = __expf(row[i] - mx);
        row[i] = e;
        sum += e;
    }
#pragma unroll
    for (int off = 32; off > 0; off >>= 1) sum += __shfl_xor(sum, off, 64);
    if (lane == 0) red[wave] = sum;
    __syncthreads();
    const float inv = 1.f / (red[0] + red[1] + red[2] + red[3]);
    for (int i = tid; i < S_; i += 256) row[i] *= inv;
}

// ---------------- pool: out[b][n*64+d] = sum_s w[b][n][s] * m[b][s][n*64+d] ----------------
__global__ __launch_bounds__(256) void k_pool(const float* __restrict__ w,          // [B][NH][S]
                                              const unsigned short* __restrict__ m, // [B][S][H] bf16
                                              float* __restrict__ out) {            // [B][H]
    const int b = blockIdx.x >> 4;
    const int n = blockIdx.x & 15;
    const int tid = threadIdx.x;
    const int d = tid & 63, g = tid >> 6;
    const float* wr = w + ((size_t)(b * NH_ + n)) * S_;
    const unsigned short* mb = m + ((size_t)b * S_) * H_ + n * HD_ + d;
    float acc = 0.f;
    for (int s = g; s < S_; s += 4)
        acc += wr[s] * bf2f(mb[(size_t)s * H_]);
    __shared__ float red[4][64];
    red[g][d] = acc;
    __syncthreads();
    if (tid < 64)
        out[b * H_ + n * HD_ + d] = red[0][d] + red[1][d] + red[2][d] + red[3][d];
}

// ---------------- gate: dst[b,s,h] = bf16( src[b,s,h] * scale[b][h] ), x8 vectorized ----------------
__global__ __launch_bounds__(256) void k_gate(const unsigned short* __restrict__ src,
                                              const float* __restrict__ scale, // [B][H]
                                              unsigned short* __restrict__ dst) {
    const size_t idx = ((size_t)blockIdx.x * 256 + threadIdx.x) * 8;
    const int b = (int)(idx >> 22);          // S_*H_ = 2^22
    const int h = (int)(idx & (H_ - 1));     // chunks of 8 never cross H boundary
    union { uint4 v; unsigned short u[8]; } x;
    x.v = *(const uint4*)(src + idx);
    const float* sc = scale + b * H_ + h;
#pragma unroll
    for (int e = 0; e < 8; e++)
        x.u[e] = f2bf(bf2f(x.u[e]) * sc[e]);
    *(uint4*)(dst + idx) = x.v;
}

extern "C" void kernel_launch(void* const* d_in, const int* in_sizes, int n_in,
                              void* d_out, int out_size, void* d_ws, size_t ws_size,
                              hipStream_t stream) {
    (void)in_sizes; (void)n_in; (void)out_size; (void)ws_size;
    const float* hs   = (const float*)d_in[0];
    const float* mask = (const float*)d_in[1];
    const float* Wq   = (const float*)d_in[2];
    const float* bq   = (const float*)d_in[3];
    const float* Wqa  = (const float*)d_in[4];
    const float* bqa  = (const float*)d_in[5];
    const float* Wk   = (const float*)d_in[6];
    const float* bk   = (const float*)d_in[7];
    const float* Wka  = (const float*)d_in[8];
    const float* bka  = (const float*)d_in[9];
    const float* Wt   = (const float*)d_in[10];
    const float* bt   = (const float*)d_in[11];
    float* out = (float*)d_out;

    const size_t NEL = (size_t)B_ * S_ * H_; // 33554432
    char* ws = (char*)d_ws;
    unsigned short* hs_bf = (unsigned short*)ws; ws += NEL * 2;            // later reused as mqk
    unsigned short* mq_bf = (unsigned short*)ws; ws += NEL * 2;
    unsigned short* mk_bf = (unsigned short*)ws; ws += NEL * 2;            // later reused as wv
    unsigned short* WTq   = (unsigned short*)ws; ws += (size_t)H_ * H_ * 2;
    unsigned short* WTk   = (unsigned short*)ws; ws += (size_t)H_ * H_ * 2;
    unsigned short* WTt   = (unsigned short*)ws; ws += (size_t)H_ * H_ * 2;
    float* qs = (float*)ws; ws += (size_t)B_ * NH_ * S_ * 4;               // reused for qks
    float* pq = (float*)ws; ws += (size_t)B_ * H_ * 4;
    float* pk = (float*)ws; ws += (size_t)B_ * H_ * 4;

    const int M = B_ * S_;
    dim3 ggrid(H_ / 128, M / 128);

    // 1) dtype prep
    k_f32_to_bf16<<<(int)(NEL / 4 / 256), 256, 0, stream>>>(hs, hs_bf, (int)(NEL / 4));
    k_transpose_bf16<<<H_ * H_ / 256, 256, 0, stream>>>(Wq, WTq);
    k_transpose_bf16<<<H_ * H_ / 256, 256, 0, stream>>>(Wk, WTk);
    k_transpose_bf16<<<H_ * H_ / 256, 256, 0, stream>>>(Wt, WTt);

    // 2) mq, mk projections
    k_gemm_bt<0><<<ggrid, 256, 0, stream>>>(hs_bf, WTq, bq, mq_bf, nullptr, M, H_, H_);
    k_gemm_bt<0><<<ggrid, 256, 0, stream>>>(hs_bf, WTk, bk, mk_bf, nullptr, M, H_, H_);

    // 3) query pooling: qs -> softmax -> pq
    k_score<<<M / 16, 256, 0, stream>>>(mq_bf, Wqa, bqa, mask, qs);
    k_softmax<<<B_ * NH_, 256, 0, stream>>>(qs);
    k_pool<<<B_ * NH_, 256, 0, stream>>>(qs, mq_bf, pq);

    // 4) mqk = mk * pq   (into hs_bf buffer)
    k_gate<<<(int)(NEL / 8 / 256), 256, 0, stream>>>(mk_bf, pq, hs_bf);

    // 5) key pooling: qks -> softmax -> pk
    k_score<<<M / 16, 256, 0, stream>>>(hs_bf, Wka, bka, mask, qs);
    k_softmax<<<B_ * NH_, 256, 0, stream>>>(qs);
    k_pool<<<B_ * NH_, 256, 0, stream>>>(qs, hs_bf, pk);

    // 6) wv = mq * pk    (into mk_bf buffer)
    k_gate<<<(int)(NEL / 8 / 256), 256, 0, stream>>>(mq_bf, pk, mk_bf);

    // 7) out = wv @ Wt + bt + mq
    k_gemm_bt<1><<<ggrid, 256, 0, stream>>>(mk_bf, WTt, bt, out, mq_bf, M, H_, H_);
}

// Round 2
// 867.151 us; speedup vs baseline: 1.5359x; 1.5359x over previous
//
#include <hip/hip_runtime.h>
#include <hip/hip_bf16.h>
#include <stdint.h>
#include <stddef.h>

#define B_  8
#define S_  4096
#define H_  1024
#define NH_ 16
#define HD_ 64
#define PCH 32   // pool S-chunks: grid = PCH * B*NH = 4096 blocks

typedef __bf16 bf16x8 __attribute__((ext_vector_type(8)));
typedef float  floatx4 __attribute__((ext_vector_type(4)));

__device__ __forceinline__ float bf2f(unsigned short u) {
    union { unsigned int i; float f; } x;
    x.i = ((unsigned int)u) << 16;
    return x.f;
}
__device__ __forceinline__ unsigned short f2bf(float f) {
    union { float f; unsigned int i; } x;
    x.f = f;
    return (unsigned short)((x.i + 0x7FFFu + ((x.i >> 16) & 1u)) >> 16);
}

// ---------------- conversion: fp32 -> bf16, vectorized x4 ----------------
__global__ __launch_bounds__(256) void k_f32_to_bf16(const float* __restrict__ src,
                                                     unsigned short* __restrict__ dst,
                                                     int n4) {
    int idx = blockIdx.x * 256 + threadIdx.x;
    if (idx >= n4) return;
    float4 v = ((const float4*)src)[idx];
    ushort4 o;
    o.x = f2bf(v.x); o.y = f2bf(v.y); o.z = f2bf(v.z); o.w = f2bf(v.w);
    ((ushort4*)dst)[idx] = o;
}

// ---------------- transpose-convert: W[k][n] fp32 -> WT[n][k] bf16 ----------------
__global__ __launch_bounds__(256) void k_transpose_bf16(const float* __restrict__ w,
                                                        unsigned short* __restrict__ wt) {
    int idx = blockIdx.x * 256 + threadIdx.x;   // 0 .. H*H-1
    int k = idx >> 10, n = idx & (H_ - 1);
    wt[(n << 10) | k] = f2bf(w[idx]);
}

// ---------------- main MFMA GEMM: C[M][N] = A[M][K] @ B[K][N] (+bias) ----------------
// A bf16 row-major [M][K]; BT bf16 [N][K] (i.e. B transposed).
// MODE 0: C written as bf16.  MODE 1: C written as fp32 with += bf2f(addsrc) (final output).
template <int MODE>
__global__ __launch_bounds__(256) void k_gemm_bt(const unsigned short* __restrict__ A,
                                                 const unsigned short* __restrict__ BT,
                                                 const float* __restrict__ bias,
                                                 void* __restrict__ Cout,
                                                 const unsigned short* __restrict__ addsrc,
                                                 int M, int N, int K) {
    constexpr int BM = 128, BN = 128, BK = 32, LDSW = 40; // pad 32->40 elems: 80B rows, conflict-free b128
    __shared__ unsigned short As[BM * LDSW];
    __shared__ unsigned short Bs[BN * LDSW];

    const int tid  = threadIdx.x;
    const int wave = tid >> 6, lane = tid & 63;
    const int quad = lane >> 4, m16 = lane & 15;
    const int wm = wave >> 1, wn = wave & 1;
    const int rowBase = blockIdx.y * BM;
    const int colBase = blockIdx.x * BN;

    floatx4 acc[4][4] = {};

    // staging: thread t loads row ar, 16-elem chunk ac (32 B = 2x uint4)
    const int ar = tid >> 1;
    const int ac = tid & 1;
    const uint4* agp = (const uint4*)(A + (size_t)(rowBase + ar) * K + ac * 16);
    const uint4* bgp = (const uint4*)(BT + (size_t)(colBase + ar) * K + ac * 16);
    uint4* asp = (uint4*)(As + ar * LDSW + ac * 16);
    uint4* bsp = (uint4*)(Bs + ar * LDSW + ac * 16);

    for (int kt = 0; kt < K; kt += BK) {
        uint4 a0 = agp[0], a1 = agp[1];
        uint4 b0 = bgp[0], b1 = bgp[1];
        agp += BK / 8; bgp += BK / 8;
        __syncthreads();
        asp[0] = a0; asp[1] = a1;
        bsp[0] = b0; bsp[1] = b1;
        __syncthreads();
        bf16x8 af[4], bfr[4];
#pragma unroll
        for (int i = 0; i < 4; i++)
            af[i] = *(const bf16x8*)(As + (wm * 64 + i * 16 + m16) * LDSW + quad * 8);
#pragma unroll
        for (int j = 0; j < 4; j++)
            bfr[j] = *(const bf16x8*)(Bs + (wn * 64 + j * 16 + m16) * LDSW + quad * 8);
#pragma unroll
        for (int i = 0; i < 4; i++)
#pragma unroll
            for (int j = 0; j < 4; j++)
                acc[i][j] = __builtin_amdgcn_mfma_f32_16x16x32_bf16(af[i], bfr[j], acc[i][j], 0, 0, 0);
    }

    // epilogue: D row = (lane>>4)*4 + r, col = lane&15  [measured layout, m89/m91]
#pragma unroll
    for (int i = 0; i < 4; i++) {
        const int row0 = rowBase + wm * 64 + i * 16 + quad * 4;
#pragma unroll
        for (int j = 0; j < 4; j++) {
            const int col = colBase + wn * 64 + j * 16 + m16;
            const float bv = bias[col];
#pragma unroll
            for (int r = 0; r < 4; r++) {
                const size_t off = (size_t)(row0 + r) * N + col;
                const float v = acc[i][j][r] + bv;
                if constexpr (MODE == 0) {
                    ((unsigned short*)Cout)[off] = f2bf(v);
                } else {
                    ((float*)Cout)[off] = v + bf2f(addsrc[off]);
                }
            }
        }
    }
}

// ---------------- score: qs[b][n][s] = (A[b,s,:]·W[:,n] + bias[n])*scale + mask[b][s] ----------------
__global__ __launch_bounds__(256) void k_score(const unsigned short* __restrict__ A, // [B*S][H] bf16
                                               const float* __restrict__ W,          // [H][NH] fp32
                                               const float* __restrict__ bias,       // [NH]
                                               const float* __restrict__ mask,       // [B][S]
                                               float* __restrict__ out) {            // [B][NH][S]
    __shared__ float Ws[H_ * NH_]; // 64 KB
    const int tid = threadIdx.x;
    for (int i = tid; i < H_ * NH_; i += 256) Ws[i] = W[i];
    __syncthreads();
    const int row = blockIdx.x * 16 + (tid >> 4); // global (b,s) row
    const int n = tid & 15;
    const int b = row >> 12, s = row & (S_ - 1);
    const unsigned short* arow = A + (size_t)row * H_;
    float dot = 0.f;
    for (int h = 0; h < H_; h += 8) {
        union { uint4 v; unsigned short u[8]; } x;
        x.v = *(const uint4*)(arow + h);
#pragma unroll
        for (int e = 0; e < 8; e++)
            dot += bf2f(x.u[e]) * Ws[(h + e) * NH_ + n];
    }
    out[((size_t)(b * NH_ + n)) * S_ + s] = (dot + bias[n]) * 0.125f + mask[row];
}

// ---------------- softmax over S, one block per (b,n) row ----------------
__global__ __launch_bounds__(256) void k_softmax(float* __restrict__ p) {
    float* row = p + (size_t)blockIdx.x * S_;
    const int tid = threadIdx.x;
    const int lane = tid & 63, wave = tid >> 6;
    __shared__ float red[4];

    float mx = -1e30f;
    for (int i = tid; i < S_; i += 256) mx = fmaxf(mx, row[i]);
#pragma unroll
    for (int off = 32; off > 0; off >>= 1) mx = fmaxf(mx, __shfl_xor(mx, off, 64));
    if (lane == 0) red[wave] = mx;
    __syncthreads();
    mx = fmaxf(fmaxf(red[0], red[1]), fmaxf(red[2], red[3]));
    __syncthreads();

    float sum = 0.f;
    for (int i = tid; i < S_; i += 256) {
        float e = __expf(row[i] - mx);
        row[i] = e;
        sum += e;
    }
#pragma unroll
    for (int off = 32; off > 0; off >>= 1) sum += __shfl_xor(sum, off, 64);
    if (lane == 0) red[wave] = sum;
    __syncthreads();
    const float inv = 1.f / (red[0] + red[1] + red[2] + red[3]);
    for (int i = tid; i < S_; i += 256) row[i] *= inv;
}

// ---------------- pool stage 1: partial[c][b][n*64+d] = sum_{s in chunk c} w[b][n][s] * m[b][s][n*64+d]
// grid (PCH, B*NH) = 4096 blocks -> ~16 blocks/CU (vs 128 blocks total before: 249us latency-bound)
__global__ __launch_bounds__(256) void k_pool1(const float* __restrict__ w,          // [B][NH][S]
                                               const unsigned short* __restrict__ m, // [B][S][H] bf16
                                               float* __restrict__ partial) {        // [PCH][B][H]
    const int c = blockIdx.x;            // S-chunk
    const int b = blockIdx.y >> 4;
    const int n = blockIdx.y & 15;
    const int tid = threadIdx.x;
    const int d = tid & 63, g = tid >> 6;
    const int s0 = c * (S_ / PCH);       // 128 rows per chunk
    const float* wr = w + ((size_t)(b * NH_ + n)) * S_;
    const unsigned short* mb = m + ((size_t)b * S_) * H_ + n * HD_ + d;
    float acc = 0.f;
#pragma unroll 4
    for (int i = 0; i < S_ / PCH / 4; i++) {
        const int s = s0 + g + 4 * i;
        acc += wr[s] * bf2f(mb[(size_t)s * H_]);
    }
    __shared__ float red[4][64];
    red[g][d] = acc;
    __syncthreads();
    if (tid < 64)
        partial[((size_t)c * B_ + b) * H_ + n * HD_ + d] =
            red[0][d] + red[1][d] + red[2][d] + red[3][d];
}

// ---------------- pool stage 2: out[b][h] = sum_c partial[c][b][h] ----------------
__global__ __launch_bounds__(256) void k_pool2(const float* __restrict__ partial,
                                               float* __restrict__ out) {
    const int idx = blockIdx.x * 256 + threadIdx.x; // 0..B*H-1
    float acc = 0.f;
#pragma unroll
    for (int c = 0; c < PCH; c++)
        acc += partial[(size_t)c * (B_ * H_) + idx];
    out[idx] = acc;
}

// ---------------- gate: dst[b,s,h] = bf16( src[b,s,h] * scale[b][h] ), x8 vectorized ----------------
__global__ __launch_bounds__(256) void k_gate(const unsigned short* __restrict__ src,
                                              const float* __restrict__ scale, // [B][H]
                                              unsigned short* __restrict__ dst) {
    const size_t idx = ((size_t)blockIdx.x * 256 + threadIdx.x) * 8;
    const int b = (int)(idx >> 22);          // S_*H_ = 2^22
    const int h = (int)(idx & (H_ - 1));     // chunks of 8 never cross H boundary
    union { uint4 v; unsigned short u[8]; } x;
    x.v = *(const uint4*)(src + idx);
    const float* sc = scale + b * H_ + h;
#pragma unroll
    for (int e = 0; e < 8; e++)
        x.u[e] = f2bf(bf2f(x.u[e]) * sc[e]);
    *(uint4*)(dst + idx) = x.v;
}

extern "C" void kernel_launch(void* const* d_in, const int* in_sizes, int n_in,
                              void* d_out, int out_size, void* d_ws, size_t ws_size,
                              hipStream_t stream) {
    (void)in_sizes; (void)n_in; (void)out_size; (void)ws_size;
    const float* hs   = (const float*)d_in[0];
    const float* mask = (const float*)d_in[1];
    const float* Wq   = (const float*)d_in[2];
    const float* bq   = (const float*)d_in[3];
    const float* Wqa  = (const float*)d_in[4];
    const float* bqa  = (const float*)d_in[5];
    const float* Wk   = (const float*)d_in[6];
    const float* bk   = (const float*)d_in[7];
    const float* Wka  = (const float*)d_in[8];
    const float* bka  = (const float*)d_in[9];
    const float* Wt   = (const float*)d_in[10];
    const float* bt   = (const float*)d_in[11];
    float* out = (float*)d_out;

    const size_t NEL = (size_t)B_ * S_ * H_; // 33554432
    char* ws = (char*)d_ws;
    unsigned short* hs_bf = (unsigned short*)ws; ws += NEL * 2;            // later reused as mqk
    unsigned short* mq_bf = (unsigned short*)ws; ws += NEL * 2;
    unsigned short* mk_bf = (unsigned short*)ws; ws += NEL * 2;            // later reused as wv
    unsigned short* WTq   = (unsigned short*)ws; ws += (size_t)H_ * H_ * 2; // free after step 2 -> pool partials
    unsigned short* WTk   = (unsigned short*)ws; ws += (size_t)H_ * H_ * 2;
    unsigned short* WTt   = (unsigned short*)ws; ws += (size_t)H_ * H_ * 2;
    float* qs = (float*)ws; ws += (size_t)B_ * NH_ * S_ * 4;               // reused for qks
    float* pq = (float*)ws; ws += (size_t)B_ * H_ * 4;
    float* pk = (float*)ws; ws += (size_t)B_ * H_ * 4;
    float* ppart = (float*)WTq; // PCH*B*H*4 = 1 MB <= 2 MB (WTq dead after projections)

    const int M = B_ * S_;
    dim3 ggrid(H_ / 128, M / 128);
    dim3 pgrid(PCH, B_ * NH_);

    // 1) dtype prep
    k_f32_to_bf16<<<(int)(NEL / 4 / 256), 256, 0, stream>>>(hs, hs_bf, (int)(NEL / 4));
    k_transpose_bf16<<<H_ * H_ / 256, 256, 0, stream>>>(Wq, WTq);
    k_transpose_bf16<<<H_ * H_ / 256, 256, 0, stream>>>(Wk, WTk);
    k_transpose_bf16<<<H_ * H_ / 256, 256, 0, stream>>>(Wt, WTt);

    // 2) mq, mk projections
    k_gemm_bt<0><<<ggrid, 256, 0, stream>>>(hs_bf, WTq, bq, mq_bf, nullptr, M, H_, H_);
    k_gemm_bt<0><<<ggrid, 256, 0, stream>>>(hs_bf, WTk, bk, mk_bf, nullptr, M, H_, H_);

    // 3) query pooling: qs -> softmax -> pq
    k_score<<<M / 16, 256, 0, stream>>>(mq_bf, Wqa, bqa, mask, qs);
    k_softmax<<<B_ * NH_, 256, 0, stream>>>(qs);
    k_pool1<<<pgrid, 256, 0, stream>>>(qs, mq_bf, ppart);
    k_pool2<<<B_ * H_ / 256, 256, 0, stream>>>(ppart, pq);

    // 4) mqk = mk * pq   (into hs_bf buffer)
    k_gate<<<(int)(NEL / 8 / 256), 256, 0, stream>>>(mk_bf, pq, hs_bf);

    // 5) key pooling: qks -> softmax -> pk
    k_score<<<M / 16, 256, 0, stream>>>(hs_bf, Wka, bka, mask, qs);
    k_softmax<<<B_ * NH_, 256, 0, stream>>>(qs);
    k_pool1<<<pgrid, 256, 0, stream>>>(qs, hs_bf, ppart);
    k_pool2<<<B_ * H_ / 256, 256, 0, stream>>>(ppart, pk);

    // 6) wv = mq * pk    (into mk_bf buffer)
    k_gate<<<(int)(NEL / 8 / 256), 256, 0, stream>>>(mq_bf, pk, mk_bf);

    // 7) out = wv @ Wt + bt + mq
    k_gemm_bt<1><<<ggrid, 256, 0, stream>>>(mk_bf, WTt, bt, out, mq_bf, M, H_, H_);
}

// Round 3
// 841.498 us; speedup vs baseline: 1.5828x; 1.0305x over previous
//
#include <hip/hip_runtime.h>
#include <hip/hip_bf16.h>
#include <stdint.h>
#include <stddef.h>

#define B_  8
#define S_  4096
#define H_  1024
#define NH_ 16
#define HD_ 64
#define PCH 32   // pool S-chunks: grid = PCH * B*NH = 4096 blocks

typedef __bf16 bf16x8 __attribute__((ext_vector_type(8)));
typedef float  floatx4 __attribute__((ext_vector_type(4)));

__device__ __forceinline__ float bf2f(unsigned short u) {
    union { unsigned int i; float f; } x;
    x.i = ((unsigned int)u) << 16;
    return x.f;
}
__device__ __forceinline__ unsigned short f2bf(float f) {
    union { float f; unsigned int i; } x;
    x.f = f;
    return (unsigned short)((x.i + 0x7FFFu + ((x.i >> 16) & 1u)) >> 16);
}

__device__ __forceinline__ void gl_lds16(const unsigned short* g, unsigned short* l) {
    __builtin_amdgcn_global_load_lds(
        (const __attribute__((address_space(1))) unsigned int*)g,
        (__attribute__((address_space(3))) unsigned int*)l,
        16, 0, 0);
}

// ---------------- conversion: fp32 -> bf16, vectorized x4 ----------------
__global__ __launch_bounds__(256) void k_f32_to_bf16(const float* __restrict__ src,
                                                     unsigned short* __restrict__ dst,
                                                     int n4) {
    int idx = blockIdx.x * 256 + threadIdx.x;
    if (idx >= n4) return;
    float4 v = ((const float4*)src)[idx];
    ushort4 o;
    o.x = f2bf(v.x); o.y = f2bf(v.y); o.z = f2bf(v.z); o.w = f2bf(v.w);
    ((ushort4*)dst)[idx] = o;
}

// ---------------- transpose-convert: W[k][n] fp32 -> WT[n][k] bf16 ----------------
__global__ __launch_bounds__(256) void k_transpose_bf16(const float* __restrict__ w,
                                                        unsigned short* __restrict__ wt) {
    int idx = blockIdx.x * 256 + threadIdx.x;   // 0 .. H*H-1
    int k = idx >> 10, n = idx & (H_ - 1);
    wt[(n << 10) | k] = f2bf(w[idx]);
}

// ---------------- main MFMA GEMM: C[M][N] = A[M][K] @ B[K][N] (+bias) ----------------
// A bf16 row-major [M][K]; BT bf16 [N][K].  Staging via global_load_lds width=16
// (m97 rung). LDS is unpadded [128][32] with XOR chunk swizzle:
//   16B chunk c of row r lives at slot c ^ ((r>>1)&3)
// -> ds_read_b128 bank group (r&1)*4 + slot covers all 8 groups 2x per quad = conflict-free.
// MODE 0: C written as bf16.  MODE 1: C written as fp32 with += bf2f(addsrc) (final output).
template <int MODE>
__global__ __launch_bounds__(256) void k_gemm_bt(const unsigned short* __restrict__ A,
                                                 const unsigned short* __restrict__ BT,
                                                 const float* __restrict__ bias,
                                                 void* __restrict__ Cout,
                                                 const unsigned short* __restrict__ addsrc,
                                                 int M, int N, int K) {
    constexpr int BM = 128, BN = 128, BK = 32;
    __shared__ unsigned short As[BM * BK]; // 8 KB
    __shared__ unsigned short Bs[BN * BK]; // 8 KB

    const int tid  = threadIdx.x;
    const int wave = tid >> 6, lane = tid & 63;
    const int quad = lane >> 4, m16 = lane & 15;
    const int wm = wave >> 1, wn = wave & 1;
    const int rowBase = blockIdx.y * BM;
    const int colBase = blockIdx.x * BN;

    floatx4 acc[4][4] = {};

    // --- staging setup: wave w loads A rows [32w,32w+32) + B rows [32w,32w+32),
    // 2 instrs each (16 rows = 64 lanes x 16 B per instr). LDS dest is
    // wave-uniform base + lane*16B: lane i -> row 16j + (i>>2), slot i&3.
    const int rl0 = 32 * wave + (lane >> 2);
    const int rl1 = rl0 + 16;
    const int c0 = (lane & 3) ^ ((rl0 >> 1) & 3);  // un-swizzled source chunk
    const int c1 = (lane & 3) ^ ((rl1 >> 1) & 3);
    const unsigned short* ga0 = A  + (size_t)(rowBase + rl0) * K + c0 * 8;
    const unsigned short* ga1 = A  + (size_t)(rowBase + rl1) * K + c1 * 8;
    const unsigned short* gb0 = BT + (size_t)(colBase + rl0) * K + c0 * 8;
    const unsigned short* gb1 = BT + (size_t)(colBase + rl1) * K + c1 * 8;
    unsigned short* la0 = As + (32 * wave) * BK;        // wave-uniform
    unsigned short* la1 = la0 + 16 * BK;
    unsigned short* lb0 = Bs + (32 * wave) * BK;
    unsigned short* lb1 = lb0 + 16 * BK;

    // --- fragment read offsets (elements), un-swizzle with same XOR
    int aoff[4], boff[4];
#pragma unroll
    for (int i = 0; i < 4; i++) {
        const int ra = wm * 64 + i * 16 + m16;
        aoff[i] = ra * BK + (quad ^ ((ra >> 1) & 3)) * 8;
        const int rb = wn * 64 + i * 16 + m16;
        boff[i] = rb * BK + (quad ^ ((rb >> 1) & 3)) * 8;
    }

    for (int kt = 0; kt < K; kt += BK) {
        __syncthreads();                 // prior-iter frag reads done before overwrite
        gl_lds16(ga0 + kt, la0);
        gl_lds16(ga1 + kt, la1);
        gl_lds16(gb0 + kt, lb0);
        gl_lds16(gb1 + kt, lb1);
        __syncthreads();                 // loads visible to all waves

        bf16x8 af[4], bfr[4];
#pragma unroll
        for (int i = 0; i < 4; i++) af[i]  = *(const bf16x8*)(As + aoff[i]);
#pragma unroll
        for (int j = 0; j < 4; j++) bfr[j] = *(const bf16x8*)(Bs + boff[j]);
#pragma unroll
        for (int i = 0; i < 4; i++)
#pragma unroll
            for (int j = 0; j < 4; j++)
                acc[i][j] = __builtin_amdgcn_mfma_f32_16x16x32_bf16(af[i], bfr[j], acc[i][j], 0, 0, 0);
    }

    // epilogue: D row = (lane>>4)*4 + r, col = lane&15  [measured layout, m89/m91]
#pragma unroll
    for (int i = 0; i < 4; i++) {
        const int row0 = rowBase + wm * 64 + i * 16 + quad * 4;
#pragma unroll
        for (int j = 0; j < 4; j++) {
            const int col = colBase + wn * 64 + j * 16 + m16;
            const float bv = bias[col];
#pragma unroll
            for (int r = 0; r < 4; r++) {
                const size_t off = (size_t)(row0 + r) * N + col;
                const float v = acc[i][j][r] + bv;
                if constexpr (MODE == 0) {
                    ((unsigned short*)Cout)[off] = f2bf(v);
                } else {
                    ((float*)Cout)[off] = v + bf2f(addsrc[off]);
                }
            }
        }
    }
}

// ---------------- score: qs[b][n][s] = (A[b,s,:]·W[:,n] + bias[n])*scale + mask[b][s] ----------------
__global__ __launch_bounds__(256) void k_score(const unsigned short* __restrict__ A, // [B*S][H] bf16
                                               const float* __restrict__ W,          // [H][NH] fp32
                                               const float* __restrict__ bias,       // [NH]
                                               const float* __restrict__ mask,       // [B][S]
                                               float* __restrict__ out) {            // [B][NH][S]
    __shared__ float Ws[H_ * NH_]; // 64 KB
    const int tid = threadIdx.x;
    for (int i = tid; i < H_ * NH_; i += 256) Ws[i] = W[i];
    __syncthreads();
    const int row = blockIdx.x * 16 + (tid >> 4); // global (b,s) row
    const int n = tid & 15;
    const int b = row >> 12, s = row & (S_ - 1);
    const unsigned short* arow = A + (size_t)row * H_;
    float dot = 0.f;
    for (int h = 0; h < H_; h += 8) {
        union { uint4 v; unsigned short u[8]; } x;
        x.v = *(const uint4*)(arow + h);
#pragma unroll
        for (int e = 0; e < 8; e++)
            dot += bf2f(x.u[e]) * Ws[(h + e) * NH_ + n];
    }
    out[((size_t)(b * NH_ + n)) * S_ + s] = (dot + bias[n]) * 0.125f + mask[row];
}

// ---------------- softmax over S, one block per (b,n) row ----------------
__global__ __launch_bounds__(256) void k_softmax(float* __restrict__ p) {
    float* row = p + (size_t)blockIdx.x * S_;
    const int tid = threadIdx.x;
    const int lane = tid & 63, wave = tid >> 6;
    __shared__ float red[4];

    float mx = -1e30f;
    for (int i = tid; i < S_; i += 256) mx = fmaxf(mx, row[i]);
#pragma unroll
    for (int off = 32; off > 0; off >>= 1) mx = fmaxf(mx, __shfl_xor(mx, off, 64));
    if (lane == 0) red[wave] = mx;
    __syncthreads();
    mx = fmaxf(fmaxf(red[0], red[1]), fmaxf(red[2], red[3]));
    __syncthreads();

    float sum = 0.f;
    for (int i = tid; i < S_; i += 256) {
        float e = __expf(row[i] - mx);
        row[i] = e;
        sum += e;
    }
#pragma unroll
    for (int off = 32; off > 0; off >>= 1) sum += __shfl_xor(sum, off, 64);
    if (lane == 0) red[wave] = sum;
    __syncthreads();
    const float inv = 1.f / (red[0] + red[1] + red[2] + red[3]);
    for (int i = tid; i < S_; i += 256) row[i] *= inv;
}

// ---------------- pool stage 1: partial[c][b][n*64+d] = sum_{s in chunk c} w[b][n][s] * m[b][s][n*64+d]
__global__ __launch_bounds__(256) void k_pool1(const float* __restrict__ w,          // [B][NH][S]
                                               const unsigned short* __restrict__ m, // [B][S][H] bf16
                                               float* __restrict__ partial) {        // [PCH][B][H]
    const int c = blockIdx.x;            // S-chunk
    const int b = blockIdx.y >> 4;
    const int n = blockIdx.y & 15;
    const int tid = threadIdx.x;
    const int d = tid & 63, g = tid >> 6;
    const int s0 = c * (S_ / PCH);       // 128 rows per chunk
    const float* wr = w + ((size_t)(b * NH_ + n)) * S_;
    const unsigned short* mb = m + ((size_t)b * S_) * H_ + n * HD_ + d;
    float acc = 0.f;
#pragma unroll 4
    for (int i = 0; i < S_ / PCH / 4; i++) {
        const int s = s0 + g + 4 * i;
        acc += wr[s] * bf2f(mb[(size_t)s * H_]);
    }
    __shared__ float red[4][64];
    red[g][d] = acc;
    __syncthreads();
    if (tid < 64)
        partial[((size_t)c * B_ + b) * H_ + n * HD_ + d] =
            red[0][d] + red[1][d] + red[2][d] + red[3][d];
}

// ---------------- pool stage 2: out[b][h] = sum_c partial[c][b][h] ----------------
__global__ __launch_bounds__(256) void k_pool2(const float* __restrict__ partial,
                                               float* __restrict__ out) {
    const int idx = blockIdx.x * 256 + threadIdx.x; // 0..B*H-1
    float acc = 0.f;
#pragma unroll
    for (int c = 0; c < PCH; c++)
        acc += partial[(size_t)c * (B_ * H_) + idx];
    out[idx] = acc;
}

// ---------------- gate: dst[b,s,h] = bf16( src[b,s,h] * scale[b][h] ), x8 vectorized ----------------
__global__ __launch_bounds__(256) void k_gate(const unsigned short* __restrict__ src,
                                              const float* __restrict__ scale, // [B][H]
                                              unsigned short* __restrict__ dst) {
    const size_t idx = ((size_t)blockIdx.x * 256 + threadIdx.x) * 8;
    const int b = (int)(idx >> 22);          // S_*H_ = 2^22
    const int h = (int)(idx & (H_ - 1));     // chunks of 8 never cross H boundary
    union { uint4 v; unsigned short u[8]; } x;
    x.v = *(const uint4*)(src + idx);
    const float* sc = scale + b * H_ + h;
#pragma unroll
    for (int e = 0; e < 8; e++)
        x.u[e] = f2bf(bf2f(x.u[e]) * sc[e]);
    *(uint4*)(dst + idx) = x.v;
}

extern "C" void kernel_launch(void* const* d_in, const int* in_sizes, int n_in,
                              void* d_out, int out_size, void* d_ws, size_t ws_size,
                              hipStream_t stream) {
    (void)in_sizes; (void)n_in; (void)out_size; (void)ws_size;
    const float* hs   = (const float*)d_in[0];
    const float* mask = (const float*)d_in[1];
    const float* Wq   = (const float*)d_in[2];
    const float* bq   = (const float*)d_in[3];
    const float* Wqa  = (const float*)d_in[4];
    const float* bqa  = (const float*)d_in[5];
    const float* Wk   = (const float*)d_in[6];
    const float* bk   = (const float*)d_in[7];
    const float* Wka  = (const float*)d_in[8];
    const float* bka  = (const float*)d_in[9];
    const float* Wt   = (const float*)d_in[10];
    const float* bt   = (const float*)d_in[11];
    float* out = (float*)d_out;

    const size_t NEL = (size_t)B_ * S_ * H_; // 33554432
    char* ws = (char*)d_ws;
    unsigned short* hs_bf = (unsigned short*)ws; ws += NEL * 2;            // later reused as mqk
    unsigned short* mq_bf = (unsigned short*)ws; ws += NEL * 2;
    unsigned short* mk_bf = (unsigned short*)ws; ws += NEL * 2;            // later reused as wv
    unsigned short* WTq   = (unsigned short*)ws; ws += (size_t)H_ * H_ * 2; // free after step 2 -> pool partials
    unsigned short* WTk   = (unsigned short*)ws; ws += (size_t)H_ * H_ * 2;
    unsigned short* WTt   = (unsigned short*)ws; ws += (size_t)H_ * H_ * 2;
    float* qs = (float*)ws; ws += (size_t)B_ * NH_ * S_ * 4;               // reused for qks
    float* pq = (float*)ws; ws += (size_t)B_ * H_ * 4;
    float* pk = (float*)ws; ws += (size_t)B_ * H_ * 4;
    float* ppart = (float*)WTq; // PCH*B*H*4 = 1 MB <= 2 MB (WTq dead after projections)

    const int M = B_ * S_;
    dim3 ggrid(H_ / 128, M / 128);
    dim3 pgrid(PCH, B_ * NH_);

    // 1) dtype prep
    k_f32_to_bf16<<<(int)(NEL / 4 / 256), 256, 0, stream>>>(hs, hs_bf, (int)(NEL / 4));
    k_transpose_bf16<<<H_ * H_ / 256, 256, 0, stream>>>(Wq, WTq);
    k_transpose_bf16<<<H_ * H_ / 256, 256, 0, stream>>>(Wk, WTk);
    k_transpose_bf16<<<H_ * H_ / 256, 256, 0, stream>>>(Wt, WTt);

    // 2) mq, mk projections
    k_gemm_bt<0><<<ggrid, 256, 0, stream>>>(hs_bf, WTq, bq, mq_bf, nullptr, M, H_, H_);
    k_gemm_bt<0><<<ggrid, 256, 0, stream>>>(hs_bf, WTk, bk, mk_bf, nullptr, M, H_, H_);

    // 3) query pooling: qs -> softmax -> pq
    k_score<<<M / 16, 256, 0, stream>>>(mq_bf, Wqa, bqa, mask, qs);
    k_softmax<<<B_ * NH_, 256, 0, stream>>>(qs);
    k_pool1<<<pgrid, 256, 0, stream>>>(qs, mq_bf, ppart);
    k_pool2<<<B_ * H_ / 256, 256, 0, stream>>>(ppart, pq);

    // 4) mqk = mk * pq   (into hs_bf buffer)
    k_gate<<<(int)(NEL / 8 / 256), 256, 0, stream>>>(mk_bf, pq, hs_bf);

    // 5) key pooling: qks -> softmax -> pk
    k_score<<<M / 16, 256, 0, stream>>>(hs_bf, Wka, bka, mask, qs);
    k_softmax<<<B_ * NH_, 256, 0, stream>>>(qs);
    k_pool1<<<pgrid, 256, 0, stream>>>(qs, hs_bf, ppart);
    k_pool2<<<B_ * H_ / 256, 256, 0, stream>>>(ppart, pk);

    // 6) wv = mq * pk    (into mk_bf buffer)
    k_gate<<<(int)(NEL / 8 / 256), 256, 0, stream>>>(mq_bf, pk, mk_bf);

    // 7) out = wv @ Wt + bt + mq
    k_gemm_bt<1><<<ggrid, 256, 0, stream>>>(mk_bf, WTt, bt, out, mq_bf, M, H_, H_);
}